// Round 15
// baseline (318.824 us; speedup 1.0000x reference)
//
#include <hip/hip_runtime.h>
#include <math.h>

// MAM dense: C[m,n] = max_k(A[m,k]*W[n,k]) + min_k(A[m,k]*W[n,k]) + bias[n]
// A: [M,K] fp32, W: [N,K] fp32 (torch layout), C: [M,N]
//
// R15: fit the accumulators in ARCH VGPRs (R14 proved v_max3 can't touch
// AGPRs; R13 showed 128 accs -> AGPR home -> 2x accvgpr inflation at full
// duty). Tm=8 x Tn=4 micro = 64 accs. A (1 B/prod) via wave-private LDS
// strips (k-major, barrier-free, R12-proven); W (0.5 B/prod) streamed
// per-lane from global as float2 -- k is the fast axis of W[N,K], so no
// transpose, no W staging. 64m x 32n tile, 4-way in-block split-K, grid
// 32x32=1024 blocks, __launch_bounds__(256,4) -> 4 waves/SIMD, ~115 VGPRs.
// VALU floor 54.6 us; predict 60-75 us main kernel.

#define BK 16
#define LDSP 68
#define STRIPF (BK * LDSP)   // 1088 floats per strip

__device__ __forceinline__ void mam_upd(float& mx, float& mn, float p0, float p1) {
    asm("v_max3_f32 %0, %1, %2, %0" : "+v"(mx) : "v"(p0), "v"(p1));
    asm("v_min3_f32 %0, %1, %2, %0" : "+v"(mn) : "v"(p0), "v"(p1));
}

__global__ __launch_bounds__(256, 4) void mam_sk(
    const float* __restrict__ A, const float* __restrict__ W,
    const float* __restrict__ bias, float* __restrict__ C,
    int M, int N, int K)
{
    // 4 wave-private A strips (4 x 16 x 68 floats = 17408 B). After the main
    // loop the same memory holds cmx/cmn (64x32 each = 16384 B).
    __shared__ __align__(16) float smem[4 * STRIPF];
    float* cmx = smem;           // 2048 floats
    float* cmn = smem + 2048;    // 2048 floats

    const int t    = threadIdx.x;
    const int w    = t >> 6;        // wave id == k-group
    const int lane = t & 63;
    const int ty   = lane >> 3;     // m micro thread: rows ty*8..ty*8+7
    const int tx   = lane & 7;      // n micro thread: cols tx*4..tx*4+3
    const int m0   = blockIdx.y * 64;
    const int n0   = blockIdx.x * 32;
    const int kc   = K >> 2;        // 256 k per wave
    const int kb0  = w * kc;
    const int npairs = kc >> 1;     // 128

    float* sAw = smem + w * STRIPF;

    // A staging: this lane owns row m0+lane of the wave's k-chunk
    const float* Ap = A + (size_t)(m0 + lane) * K + kb0;
    // W stream base: 4 rows n0+tx*4 .. +3, k-major (native layout)
    const float* Wb = W + (size_t)(n0 + tx * 4) * K + kb0;

    float mx[8][4], mn[8][4];
#pragma unroll
    for (int i = 0; i < 8; ++i)
#pragma unroll
        for (int c = 0; c < 4; ++c) {
            mx[i][c] = -INFINITY;
            mn[i][c] =  INFINITY;
        }

    // W ring: current + next k-pair
    float2 wc[4], wn[4];
#pragma unroll
    for (int c = 0; c < 4; ++c)
        wc[c] = *(const float2*)(Wb + (size_t)c * K);

    const int nStages = kc / BK;    // 16
    for (int s = 0; s < nStages; ++s) {
        // ---- stage A[64 rows][16 k] into this wave's strip, k-major ----
        float4 st0 = *(const float4*)(Ap + 0);
        float4 st1 = *(const float4*)(Ap + 4);
        float4 st2 = *(const float4*)(Ap + 8);
        float4 st3 = *(const float4*)(Ap + 12);
        Ap += BK;
        sAw[ 0 * LDSP + lane] = st0.x;
        sAw[ 1 * LDSP + lane] = st0.y;
        sAw[ 2 * LDSP + lane] = st0.z;
        sAw[ 3 * LDSP + lane] = st0.w;
        sAw[ 4 * LDSP + lane] = st1.x;
        sAw[ 5 * LDSP + lane] = st1.y;
        sAw[ 6 * LDSP + lane] = st1.z;
        sAw[ 7 * LDSP + lane] = st1.w;
        sAw[ 8 * LDSP + lane] = st2.x;
        sAw[ 9 * LDSP + lane] = st2.y;
        sAw[10 * LDSP + lane] = st2.z;
        sAw[11 * LDSP + lane] = st2.w;
        sAw[12 * LDSP + lane] = st3.x;
        sAw[13 * LDSP + lane] = st3.y;
        sAw[14 * LDSP + lane] = st3.z;
        sAw[15 * LDSP + lane] = st3.w;
        // no barrier: strip is wave-private; same-wave DS ops are ordered

#pragma unroll
        for (int kp = 0; kp < BK / 2; ++kp) {
            // prefetch next W k-pair (wraps harmlessly at the very end)
            const int jn = (s * 8 + kp + 1) & (npairs - 1);
#pragma unroll
            for (int c = 0; c < 4; ++c)
                wn[c] = *(const float2*)(Wb + (size_t)c * K + 2 * jn);

            const int k = kp * 2;
            float4 a0lo = *(const float4*)&sAw[(k    ) * LDSP + ty * 8];
            float4 a0hi = *(const float4*)&sAw[(k    ) * LDSP + ty * 8 + 4];
            float4 a1lo = *(const float4*)&sAw[(k + 1) * LDSP + ty * 8];
            float4 a1hi = *(const float4*)&sAw[(k + 1) * LDSP + ty * 8 + 4];

            float a0[8] = {a0lo.x, a0lo.y, a0lo.z, a0lo.w,
                           a0hi.x, a0hi.y, a0hi.z, a0hi.w};
            float a1[8] = {a1lo.x, a1lo.y, a1lo.z, a1lo.w,
                           a1hi.x, a1hi.y, a1hi.z, a1hi.w};

#pragma unroll
            for (int c = 0; c < 4; ++c) {
                const float w0 = wc[c].x;   // k
                const float w1 = wc[c].y;   // k+1
#pragma unroll
                for (int i = 0; i < 8; ++i) {
                    float p0 = a0[i] * w0;
                    float p1 = a1[i] * w1;
                    mam_upd(mx[i][c], mn[i][c], p0, p1);
                }
            }
#pragma unroll
            for (int c = 0; c < 4; ++c)
                wc[c] = wn[c];
        }
    }

    // strips now dead; cmx/cmn overlap them -> drain all waves first
    __syncthreads();

    // ---- cross-wave combine: 4 sequential merge rounds through LDS ----
    for (int rnd = 0; rnd < 4; ++rnd) {
        if (w == rnd) {
#pragma unroll
            for (int i = 0; i < 8; ++i)
#pragma unroll
                for (int c = 0; c < 4; ++c) {
                    const int idx = (ty * 8 + i) * 32 + tx * 4 + c;
                    if (rnd == 0) {
                        cmx[idx] = mx[i][c];
                        cmn[idx] = mn[i][c];
                    } else {
                        cmx[idx] = fmaxf(cmx[idx], mx[i][c]);
                        cmn[idx] = fminf(cmn[idx], mn[i][c]);
                    }
                }
        }
        __syncthreads();
    }

    // ---- bias + store: thread t -> row t>>2, col-group t&3 (8 cols) ----
    {
        const int r  = t >> 2;          // 0..63
        const int cg = t & 3;           // 0..3
        const int idx = r * 32 + cg * 8;
        float4 x0 = *(const float4*)&cmx[idx];
        float4 x1 = *(const float4*)&cmx[idx + 4];
        float4 n0v = *(const float4*)&cmn[idx];
        float4 n1v = *(const float4*)&cmn[idx + 4];
        float4 b0 = *(const float4*)(bias + n0 + cg * 8);
        float4 b1 = *(const float4*)(bias + n0 + cg * 8 + 4);
        float4 o0, o1;
        o0.x = x0.x + n0v.x + b0.x;
        o0.y = x0.y + n0v.y + b0.y;
        o0.z = x0.z + n0v.z + b0.z;
        o0.w = x0.w + n0v.w + b0.w;
        o1.x = x1.x + n1v.x + b1.x;
        o1.y = x1.y + n1v.y + b1.y;
        o1.z = x1.z + n1v.z + b1.z;
        o1.w = x1.w + n1v.w + b1.w;
        float4* p = (float4*)(C + (size_t)(m0 + r) * N + n0 + cg * 8);
        p[0] = o0;
        p[1] = o1;
    }
}

// ---- fallback (proven R2 kernel) for shapes the fast path can't take ----
#define BM 64
#define BN 64
#define FBK 32
#define LDSW 68

__device__ __forceinline__ void mam_upd_fb(float& mx, float& mn, float p0, float p1) {
    float nmx, nmn;
    asm("v_max3_f32 %0, %1, %2, %3" : "=v"(nmx) : "v"(p0), "v"(p1), "v"(mx));
    asm("v_min3_f32 %0, %1, %2, %3" : "=v"(nmn) : "v"(p0), "v"(p1), "v"(mn));
    mx = nmx;
    mn = nmn;
}

__global__ __launch_bounds__(256) void mam_fallback(
    const float* __restrict__ A, const float* __restrict__ W,
    const float* __restrict__ bias, float* __restrict__ C,
    int M, int N, int K)
{
    __shared__ float Asf[FBK][LDSW];
    __shared__ float Wsf[FBK][LDSW];

    const int t  = threadIdx.x;
    const int tx = t & 15;
    const int ty = t >> 4;
    const int m0 = blockIdx.y * BM;
    const int n0 = blockIdx.x * BN;
    const int r  = t >> 3;
    const int kq = t & 7;

    const float* Aptr = A + (size_t)(m0 + r) * K + kq * 4;
    const float* Wptr = W + (size_t)(n0 + r) * K + kq * 4;

    float vmax[4][4], vmin[4][4];
#pragma unroll
    for (int i = 0; i < 4; ++i)
#pragma unroll
        for (int j = 0; j < 4; ++j) {
            vmax[i][j] = -INFINITY;
            vmin[i][j] =  INFINITY;
        }

    for (int k0 = 0; k0 < K; k0 += FBK) {
        float4 a0 = *(const float4*)(Aptr);
        float4 a1 = *(const float4*)(Aptr + (size_t)32 * K);
        float4 w0 = *(const float4*)(Wptr);
        float4 w1 = *(const float4*)(Wptr + (size_t)32 * K);
        Aptr += FBK;
        Wptr += FBK;

        const int kk = kq * 4;
        Asf[kk + 0][r]      = a0.x;
        Asf[kk + 1][r]      = a0.y;
        Asf[kk + 2][r]      = a0.z;
        Asf[kk + 3][r]      = a0.w;
        Asf[kk + 0][r + 32] = a1.x;
        Asf[kk + 1][r + 32] = a1.y;
        Asf[kk + 2][r + 32] = a1.z;
        Asf[kk + 3][r + 32] = a1.w;

        Wsf[kk + 0][r]      = w0.x;
        Wsf[kk + 1][r]      = w0.y;
        Wsf[kk + 2][r]      = w0.z;
        Wsf[kk + 3][r]      = w0.w;
        Wsf[kk + 0][r + 32] = w1.x;
        Wsf[kk + 1][r + 32] = w1.y;
        Wsf[kk + 2][r + 32] = w1.z;
        Wsf[kk + 3][r + 32] = w1.w;

        __syncthreads();

#pragma unroll
        for (int k = 0; k < FBK; k += 2) {
            float4 ta0 = *(const float4*)&Asf[k    ][ty * 4];
            float4 ta1 = *(const float4*)&Asf[k + 1][ty * 4];
            float4 tb0 = *(const float4*)&Wsf[k    ][tx * 4];
            float4 tb1 = *(const float4*)&Wsf[k + 1][tx * 4];

            float a0v[4] = {ta0.x, ta0.y, ta0.z, ta0.w};
            float a1v[4] = {ta1.x, ta1.y, ta1.z, ta1.w};
            float b0v[4] = {tb0.x, tb0.y, tb0.z, tb0.w};
            float b1v[4] = {tb1.x, tb1.y, tb1.z, tb1.w};

#pragma unroll
            for (int i = 0; i < 4; ++i)
#pragma unroll
                for (int j = 0; j < 4; ++j) {
                    float p0 = a0v[i] * b0v[j];
                    float p1 = a1v[i] * b1v[j];
                    mam_upd_fb(vmax[i][j], vmin[i][j], p0, p1);
                }
        }
        __syncthreads();
    }

    float4 bv = *(const float4*)(bias + n0 + tx * 4);
#pragma unroll
    for (int i = 0; i < 4; ++i) {
        float4 o;
        o.x = vmax[i][0] + vmin[i][0] + bv.x;
        o.y = vmax[i][1] + vmin[i][1] + bv.y;
        o.z = vmax[i][2] + vmin[i][2] + bv.z;
        o.w = vmax[i][3] + vmin[i][3] + bv.w;
        *(float4*)(C + (size_t)(m0 + ty * 4 + i) * N + n0 + tx * 4) = o;
    }
}

extern "C" void kernel_launch(void* const* d_in, const int* in_sizes, int n_in,
                              void* d_out, int out_size, void* d_ws, size_t ws_size,
                              hipStream_t stream) {
    const float* x    = (const float*)d_in[0];
    const float* w    = (const float*)d_in[1];
    const float* bias = (const float*)d_in[2];
    float* out = (float*)d_out;

    const int N = in_sizes[2];
    const int K = in_sizes[1] / N;
    const int M = in_sizes[0] / K;

    // fast path: K/4 divisible by 16, 64|M, 32|N
    const bool fast_ok = (K % 64 == 0) && (M % 64 == 0) && (N % 32 == 0);

    if (fast_ok) {
        dim3 grid(N / 32, M / 64);   // (32, 32) = 1024 blocks
        mam_sk<<<grid, 256, 0, stream>>>(x, w, bias, out, M, N, K);
    } else {
        dim3 grid(N / BN, M / BM);
        mam_fallback<<<grid, 256, 0, stream>>>(x, w, bias, out, M, N, K);
    }
}

// Round 16
// 155.176 us; speedup vs baseline: 2.0546x; 2.0546x over previous
//
#include <hip/hip_runtime.h>
#include <math.h>

// MAM dense: C[m,n] = max_k(A[m,k]*W[n,k]) + min_k(A[m,k]*W[n,k]) + bias[n]
// A: [M,K] fp32, W: [N,K] fp32 (torch layout), C: [M,N]
//
// R16 = R13 shell with NATIVE fmaxf/fminf accumulate (no inline asm).
// R11/R13/R15 forensics: any accumulator threaded through "v"-constrained
// asm gets AGPR-homed by the allocator (unified-file spill), paying
// v_accvgpr_read/write per update -> 2x instruction inflation at full duty
// (103 us) or worse. Native maxnum/minnum chains let ISel fuse to
// v_max3_f32/v_min3_f32 AND let the allocator keep accumulators in arch
// VGPRs (budget 256 at waves_per_eu(2,2); demand ~190). Everything else
// identical to the measured R13: TS=64, 4-wave in-block split-K, 8x8 micro,
// barrier-free main loop, LDS union 34.8 KB, grid 512 blocks.

#define TS 64
#define BK 16
#define LDSP 68
#define STRIPF (BK * LDSP)   // 1088 floats per strip

__device__ __forceinline__ void mam_upd(float& mx, float& mn, float p0, float p1) {
    mx = fmaxf(fmaxf(p0, p1), mx);   // -> v_max3_f32 (ISel maxnum combine)
    mn = fminf(fminf(p0, p1), mn);   // -> v_min3_f32
}

__global__
__attribute__((amdgpu_flat_work_group_size(256, 256)))
__attribute__((amdgpu_waves_per_eu(2, 2)))
void mam_sk(
    const float* __restrict__ A, const float* __restrict__ W,
    const float* __restrict__ bias, float* __restrict__ C,
    int M, int N, int K)
{
    // union: [0..4*STRIPF) sA strips, [4*STRIPF..8*STRIPF) sW strips;
    // after the main loop (barrier) the same memory holds cmx/cmn (64x64 each).
    __shared__ __align__(16) float smem[8 * STRIPF];   // 34816 B
    float* cmx = smem;
    float* cmn = smem + TS * TS;

    const int t    = threadIdx.x;
    const int w    = t >> 6;        // wave id == k-group
    const int lane = t & 63;
    const int ty   = lane >> 3;     // m micro thread (8 rows)
    const int tx   = lane & 7;      // n micro thread (8 cols)
    const int m0   = blockIdx.y * TS;
    const int n0   = blockIdx.x * TS;
    const int kc   = K >> 2;        // 256 k per wave
    const int kb0  = w * kc;

    const int sr = lane >> 2;       // staging row 0..15
    const int sc = lane & 3;        // staging k-quad 0..3

    float* sAw = smem + (size_t)w * STRIPF;          // this wave's A strip
    float* sWw = smem + (size_t)(4 + w) * STRIPF;    // this wave's W strip

    const float* Ap = A + (size_t)(m0 + sr) * K + kb0 + sc * 4;
    const float* Wp = W + (size_t)(n0 + sr) * K + kb0 + sc * 4;

    float mx[8][8], mn[8][8];
#pragma unroll
    for (int i = 0; i < 8; ++i)
#pragma unroll
        for (int j = 0; j < 8; ++j) {
            mx[i][j] = -INFINITY;
            mn[i][j] =  INFINITY;
        }

    float4 ra[4], rw[4];
#pragma unroll
    for (int q = 0; q < 4; ++q) {
        ra[q] = *(const float4*)(Ap + (size_t)q * 16 * K);
        rw[q] = *(const float4*)(Wp + (size_t)q * 16 * K);
    }
    Ap += BK;
    Wp += BK;

    const int nStages = kc / BK;    // 16
    for (int s = 0; s < nStages; ++s) {
        // scatter current stage into this wave's strip (no barrier: strip is
        // wave-private; same-wave DS ops are ordered)
#pragma unroll
        for (int q = 0; q < 4; ++q) {
            const int mI = sr + q * 16;
            sAw[(sc * 4 + 0) * LDSP + mI] = ra[q].x;
            sAw[(sc * 4 + 1) * LDSP + mI] = ra[q].y;
            sAw[(sc * 4 + 2) * LDSP + mI] = ra[q].z;
            sAw[(sc * 4 + 3) * LDSP + mI] = ra[q].w;
            sWw[(sc * 4 + 0) * LDSP + mI] = rw[q].x;
            sWw[(sc * 4 + 1) * LDSP + mI] = rw[q].y;
            sWw[(sc * 4 + 2) * LDSP + mI] = rw[q].z;
            sWw[(sc * 4 + 3) * LDSP + mI] = rw[q].w;
        }
        // prefetch next stage while computing this one
        if (s + 1 < nStages) {
#pragma unroll
            for (int q = 0; q < 4; ++q) {
                ra[q] = *(const float4*)(Ap + (size_t)q * 16 * K);
                rw[q] = *(const float4*)(Wp + (size_t)q * 16 * K);
            }
            Ap += BK;
            Wp += BK;
        }

#pragma unroll
        for (int k = 0; k < BK; k += 2) {
            float4 a00 = *(const float4*)&sAw[(k    ) * LDSP + ty * 8];
            float4 a01 = *(const float4*)&sAw[(k    ) * LDSP + ty * 8 + 4];
            float4 a10 = *(const float4*)&sAw[(k + 1) * LDSP + ty * 8];
            float4 a11 = *(const float4*)&sAw[(k + 1) * LDSP + ty * 8 + 4];
            float4 w00 = *(const float4*)&sWw[(k    ) * LDSP + tx * 8];
            float4 w01 = *(const float4*)&sWw[(k    ) * LDSP + tx * 8 + 4];
            float4 w10 = *(const float4*)&sWw[(k + 1) * LDSP + tx * 8];
            float4 w11 = *(const float4*)&sWw[(k + 1) * LDSP + tx * 8 + 4];

            float a0[8] = {a00.x, a00.y, a00.z, a00.w, a01.x, a01.y, a01.z, a01.w};
            float a1[8] = {a10.x, a10.y, a10.z, a10.w, a11.x, a11.y, a11.z, a11.w};
            float b0[8] = {w00.x, w00.y, w00.z, w00.w, w01.x, w01.y, w01.z, w01.w};
            float b1[8] = {w10.x, w10.y, w10.z, w10.w, w11.x, w11.y, w11.z, w11.w};

#pragma unroll
            for (int i = 0; i < 8; ++i)
#pragma unroll
                for (int j = 0; j < 8; ++j) {
                    float p0 = a0[i] * b0[j];
                    float p1 = a1[i] * b1[j];
                    mam_upd(mx[i][j], mn[i][j], p0, p1);
                }
        }
    }

    // strips now dead; cmx/cmn overlap them -> drain all waves first
    __syncthreads();

    // ---- cross-wave combine: sequential merge rounds through LDS ----
    for (int rnd = 0; rnd < 4; ++rnd) {
        if (w == rnd) {
#pragma unroll
            for (int i = 0; i < 8; ++i)
#pragma unroll
                for (int j = 0; j < 8; ++j) {
                    const int idx = (ty * 8 + i) * TS + tx * 8 + j;
                    if (rnd == 0) {
                        cmx[idx] = mx[i][j];
                        cmn[idx] = mn[i][j];
                    } else {
                        cmx[idx] = fmaxf(cmx[idx], mx[i][j]);
                        cmn[idx] = fminf(cmn[idx], mn[i][j]);
                    }
                }
        }
        __syncthreads();
    }

    // ---- bias + store: wave w writes micro-rows i = {2w, 2w+1} ----
    float4 blo = *(const float4*)(bias + n0 + tx * 8);
    float4 bhi = *(const float4*)(bias + n0 + tx * 8 + 4);
#pragma unroll
    for (int i2 = 0; i2 < 2; ++i2) {
        const int i   = w * 2 + i2;
        const int row = ty * 8 + i;
        const int idx = row * TS + tx * 8;
        float4 o0, o1;
        o0.x = cmx[idx + 0] + cmn[idx + 0] + blo.x;
        o0.y = cmx[idx + 1] + cmn[idx + 1] + blo.y;
        o0.z = cmx[idx + 2] + cmn[idx + 2] + blo.z;
        o0.w = cmx[idx + 3] + cmn[idx + 3] + blo.w;
        o1.x = cmx[idx + 4] + cmn[idx + 4] + bhi.x;
        o1.y = cmx[idx + 5] + cmn[idx + 5] + bhi.y;
        o1.z = cmx[idx + 6] + cmn[idx + 6] + bhi.z;
        o1.w = cmx[idx + 7] + cmn[idx + 7] + bhi.w;
        float4* p = (float4*)(C + (size_t)(m0 + row) * N + n0 + tx * 8);
        p[0] = o0;
        p[1] = o1;
    }
}

// ---- fallback (proven R2 kernel) for shapes the fast path can't take ----
#define BM 64
#define BN 64
#define FBK 32
#define LDSW 68

__device__ __forceinline__ void mam_upd_fb(float& mx, float& mn, float p0, float p1) {
    mx = fmaxf(fmaxf(p0, p1), mx);
    mn = fminf(fminf(p0, p1), mn);
}

__global__ __launch_bounds__(256) void mam_fallback(
    const float* __restrict__ A, const float* __restrict__ W,
    const float* __restrict__ bias, float* __restrict__ C,
    int M, int N, int K)
{
    __shared__ float Asf[FBK][LDSW];
    __shared__ float Wsf[FBK][LDSW];

    const int t  = threadIdx.x;
    const int tx = t & 15;
    const int ty = t >> 4;
    const int m0 = blockIdx.y * BM;
    const int n0 = blockIdx.x * BN;
    const int r  = t >> 3;
    const int kq = t & 7;

    const float* Aptr = A + (size_t)(m0 + r) * K + kq * 4;
    const float* Wptr = W + (size_t)(n0 + r) * K + kq * 4;

    float vmax[4][4], vmin[4][4];
#pragma unroll
    for (int i = 0; i < 4; ++i)
#pragma unroll
        for (int j = 0; j < 4; ++j) {
            vmax[i][j] = -INFINITY;
            vmin[i][j] =  INFINITY;
        }

    for (int k0 = 0; k0 < K; k0 += FBK) {
        float4 a0 = *(const float4*)(Aptr);
        float4 a1 = *(const float4*)(Aptr + (size_t)32 * K);
        float4 w0 = *(const float4*)(Wptr);
        float4 w1 = *(const float4*)(Wptr + (size_t)32 * K);
        Aptr += FBK;
        Wptr += FBK;

        const int kk = kq * 4;
        Asf[kk + 0][r]      = a0.x;
        Asf[kk + 1][r]      = a0.y;
        Asf[kk + 2][r]      = a0.z;
        Asf[kk + 3][r]      = a0.w;
        Asf[kk + 0][r + 32] = a1.x;
        Asf[kk + 1][r + 32] = a1.y;
        Asf[kk + 2][r + 32] = a1.z;
        Asf[kk + 3][r + 32] = a1.w;

        Wsf[kk + 0][r]      = w0.x;
        Wsf[kk + 1][r]      = w0.y;
        Wsf[kk + 2][r]      = w0.z;
        Wsf[kk + 3][r]      = w0.w;
        Wsf[kk + 0][r + 32] = w1.x;
        Wsf[kk + 1][r + 32] = w1.y;
        Wsf[kk + 2][r + 32] = w1.z;
        Wsf[kk + 3][r + 32] = w1.w;

        __syncthreads();

#pragma unroll
        for (int k = 0; k < FBK; k += 2) {
            float4 ta0 = *(const float4*)&Asf[k    ][ty * 4];
            float4 ta1 = *(const float4*)&Asf[k + 1][ty * 4];
            float4 tb0 = *(const float4*)&Wsf[k    ][tx * 4];
            float4 tb1 = *(const float4*)&Wsf[k + 1][tx * 4];

            float a0v[4] = {ta0.x, ta0.y, ta0.z, ta0.w};
            float a1v[4] = {ta1.x, ta1.y, ta1.z, ta1.w};
            float b0v[4] = {tb0.x, tb0.y, tb0.z, tb0.w};
            float b1v[4] = {tb1.x, tb1.y, tb1.z, tb1.w};

#pragma unroll
            for (int i = 0; i < 4; ++i)
#pragma unroll
                for (int j = 0; j < 4; ++j) {
                    float p0 = a0v[i] * b0v[j];
                    float p1 = a1v[i] * b1v[j];
                    mam_upd_fb(vmax[i][j], vmin[i][j], p0, p1);
                }
        }
        __syncthreads();
    }

    float4 bv = *(const float4*)(bias + n0 + tx * 4);
#pragma unroll
    for (int i = 0; i < 4; ++i) {
        float4 o;
        o.x = vmax[i][0] + vmin[i][0] + bv.x;
        o.y = vmax[i][1] + vmin[i][1] + bv.y;
        o.z = vmax[i][2] + vmin[i][2] + bv.z;
        o.w = vmax[i][3] + vmin[i][3] + bv.w;
        *(float4*)(C + (size_t)(m0 + ty * 4 + i) * N + n0 + tx * 4) = o;
    }
}

extern "C" void kernel_launch(void* const* d_in, const int* in_sizes, int n_in,
                              void* d_out, int out_size, void* d_ws, size_t ws_size,
                              hipStream_t stream) {
    const float* x    = (const float*)d_in[0];
    const float* w    = (const float*)d_in[1];
    const float* bias = (const float*)d_in[2];
    float* out = (float*)d_out;

    const int N = in_sizes[2];
    const int K = in_sizes[1] / N;
    const int M = in_sizes[0] / K;

    const bool fast_ok = (K % (4 * BK) == 0) && (M % TS == 0) && (N % TS == 0);

    if (fast_ok) {
        dim3 grid(N / TS, M / TS);   // (16, 32) = 512 blocks
        mam_sk<<<grid, 256, 0, stream>>>(x, w, bias, out, M, N, K);
    } else {
        dim3 grid(N / BN, M / BM);
        mam_fallback<<<grid, 256, 0, stream>>>(x, w, bias, out, M, N, K);
    }
}